// Round 1
// baseline (2734.976 us; speedup 1.0000x reference)
//
#include <hip/hip_runtime.h>
#include <hip/hip_bf16.h>

typedef __attribute__((ext_vector_type(4))) float f32x4;
typedef __attribute__((ext_vector_type(8))) short short8;
typedef __attribute__((ext_vector_type(4))) unsigned int u32x4;
typedef __attribute__((ext_vector_type(4))) unsigned short u16x4;

static __device__ __forceinline__ unsigned short f2bf(float f){
  unsigned u = __builtin_bit_cast(unsigned, f);
  u += 0x7FFFu + ((u >> 16) & 1u);
  return (unsigned short)(u >> 16);
}
static __device__ __forceinline__ float bf2f(unsigned short b){
  return __builtin_bit_cast(float, ((unsigned)b) << 16);
}
static __device__ __forceinline__ f32x4 mfma16(short8 a, short8 b, f32x4 c){
  return __builtin_amdgcn_mfma_f32_16x16x32_bf16(a, b, c, 0, 0, 0);
}
static __device__ __forceinline__ float sigf(float x){ return 1.f/(1.f + __expf(-x)); }
static __device__ __forceinline__ float tanhfast(float x){
  float e = __expf(2.f*x);
  return (e - 1.f) / (e + 1.f);
}

// ---------------------------------------------------------------------------
// fp32 -> bf16 weight conversion (head_W + 7 small matrices of 196608 elems)
// ---------------------------------------------------------------------------
__global__ __launch_bounds__(256) void k_cvt(
    const float* __restrict__ sh, unsigned short* __restrict__ dh,
    const float* __restrict__ s0, const float* __restrict__ s1,
    const float* __restrict__ s2, const float* __restrict__ s3,
    const float* __restrict__ s4, const float* __restrict__ s5,
    const float* __restrict__ s6,
    unsigned short* __restrict__ d0, unsigned short* __restrict__ d1,
    unsigned short* __restrict__ d2, unsigned short* __restrict__ d3,
    unsigned short* __restrict__ d4, unsigned short* __restrict__ d5,
    unsigned short* __restrict__ d6)
{
  const long NH4 = 2048000;   // head: 8,192,000 floats / 4
  const long NS4 = 49152;     // small: 196,608 floats / 4
  const long total = NH4 + 7*NS4;
  for (long idx = (long)blockIdx.x*blockDim.x + threadIdx.x; idx < total;
       idx += (long)gridDim.x*blockDim.x) {
    const float* s; unsigned short* d; long off;
    if (idx < NH4) { s = sh; d = dh; off = idx; }
    else {
      long r = idx - NH4; int mat = (int)(r / NS4); off = r - (long)mat*NS4;
      switch (mat) {
        case 0: s=s0; d=d0; break;  case 1: s=s1; d=d1; break;
        case 2: s=s2; d=d2; break;  case 3: s=s3; d=d3; break;
        case 4: s=s4; d=d4; break;  case 5: s=s5; d=d5; break;
        default: s=s6; d=d6; break;
      }
    }
    f32x4 v = ((const f32x4*)s)[off];
    u16x4 o2;
    o2[0]=f2bf(v[0]); o2[1]=f2bf(v[1]); o2[2]=f2bf(v[2]); o2[3]=f2bf(v[3]);
    ((u16x4*)d)[off] = o2;
  }
}

// ---------------------------------------------------------------------------
// Generic MFMA GEMM: out[M][N] = gatherA[M][Ktot] @ W[N][Ktot]^T + bias
//   A rows gathered from fp32 table(s) (ids optional, concat optional).
//   tile: 64 rows x 128 cols per block (256 thr / 4 waves, wave = 16 rows).
//   EPI 0: store bf16.  EPI 1: tanh, store fp32.
// ---------------------------------------------------------------------------
template<int TN, int TS, int EPI>
__global__ __launch_bounds__(256) void k_gemm(
    const float* __restrict__ tabA, int ldA,
    const float* __restrict__ tabB2, int ldB2, int K1,
    const int* __restrict__ ids,
    const unsigned short* __restrict__ W,   // [N][Ktot] bf16
    const float* __restrict__ bias,         // [N]
    int M, int Ktot,
    void* __restrict__ outp, int ldOut)
{
  const int bm = blockIdx.x, bn = blockIdx.y;
  const int tid = threadIdx.x;
  const int lane = tid & 63, w = tid >> 6;
  const int l15 = lane & 15, l4 = lane >> 4;

  const int r_g = bm*64 + w*16 + l15;
  const int r_c = (r_g < M) ? r_g : (M-1);
  long row_src;
  if (ids) { int ii = (r_c / TN) * TS + (r_c % TN); row_src = ids[ii]; }
  else row_src = r_c;

  const int kchunk = l4 * 8;
  const int ncol0 = bn*128 + l15;

  f32x4 acc[8];
  #pragma unroll
  for (int i=0;i<8;i++){ f32x4 z4 = {0.f,0.f,0.f,0.f}; acc[i]=z4; }

  const int KB = Ktot >> 5;
  for (int kb = 0; kb < KB; ++kb) {
    int k = kb*32 + kchunk;
    const float* ap;
    if (tabB2 && k >= K1) ap = tabB2 + row_src*(long)ldB2 + (k - K1);
    else                  ap = tabA  + row_src*(long)ldA  + k;
    f32x4 a0 = *(const f32x4*)ap;
    f32x4 a1 = *(const f32x4*)(ap + 4);
    short8 afr;
    afr[0]=(short)f2bf(a0[0]); afr[1]=(short)f2bf(a0[1]);
    afr[2]=(short)f2bf(a0[2]); afr[3]=(short)f2bf(a0[3]);
    afr[4]=(short)f2bf(a1[0]); afr[5]=(short)f2bf(a1[1]);
    afr[6]=(short)f2bf(a1[2]); afr[7]=(short)f2bf(a1[3]);
    #pragma unroll
    for (int ct=0; ct<8; ++ct) {
      int n = ncol0 + ct*16;
      short8 bfr = *(const short8*)(W + (long)n*Ktot + k);
      acc[ct] = mfma16(afr, bfr, acc[ct]);
    }
  }

  #pragma unroll
  for (int ct=0; ct<8; ++ct) {
    int n = ncol0 + ct*16;
    float bv = bias[n];
    #pragma unroll
    for (int q=0; q<4; ++q) {
      int rr = bm*64 + w*16 + l4*4 + q;
      if (rr < M) {
        float v = acc[ct][q] + bv;
        if (EPI == 1) ((float*)outp)[(long)rr*ldOut + n] = tanhfast(v);
        else ((unsigned short*)outp)[(long)rr*ldOut + n] = f2bf(v);
      }
    }
  }
}

// ---------------------------------------------------------------------------
// GRU recurrence: 16 rows per block, Whh register-resident (bf16 frags).
//   block = 256 threads (4 waves); wave w owns gate cols [w*192, w*192+192).
//   per step: hg = h @ Whh^T (MFMA) -> LDS; then gate math per (row,j).
// ---------------------------------------------------------------------------
__global__ __launch_bounds__(256, 1) void k_gru(
    const unsigned short* __restrict__ Whh,  // [768][256] bf16
    const float* __restrict__ bhh,           // [768]
    const unsigned short* __restrict__ xg,   // [(grow*T+t)][768] bf16
    const int* __restrict__ mask,            // [(grow*T+t)] or null
    const float* __restrict__ h0,            // [R][256] or null
    float* __restrict__ hN,                  // [R][256] or null
    unsigned short* __restrict__ outs,       // [(grow*T+t)][256] bf16 or null
    int T)
{
  __shared__ unsigned short h_bf[16][264];   // +8 bf16 pad -> 528B row stride
  __shared__ float hg[16][772];              // +4 f32 pad

  const int tid = threadIdx.x;
  const int lane = tid & 63;
  const int w = tid >> 6;                    // 0..3
  const int rowbase = blockIdx.x * 16;
  const int l15 = lane & 15, l4 = lane >> 4;

  // step-invariant Whh fragments in registers: 12 col-tiles x 8 k-blocks
  short8 Bf[12][8];
  {
    const int n0 = w*192 + l15;
    #pragma unroll
    for (int ct=0; ct<12; ++ct)
      #pragma unroll
      for (int kb=0; kb<8; ++kb)
        Bf[ct][kb] = *(const short8*)(Whh + (long)(n0+ct*16)*256 + kb*32 + l4*8);
  }

  const int j = tid;                         // hidden unit 0..255
  float h[16];
  const float b_r = bhh[j], b_z = bhh[256+j], b_n = bhh[512+j];
  #pragma unroll
  for (int i=0; i<16; ++i) {
    float hv = h0 ? h0[(long)(rowbase+i)*256 + j] : 0.f;
    h[i] = hv;
    h_bf[i][j] = f2bf(hv);
  }
  __syncthreads();

  for (int t=0; t<T; ++t) {
    // ---- MFMA phase: hg = h @ Whh^T ----
    f32x4 acc[12];
    #pragma unroll
    for (int ct=0; ct<12; ++ct){ f32x4 z4={0.f,0.f,0.f,0.f}; acc[ct]=z4; }
    #pragma unroll
    for (int kb=0; kb<8; ++kb) {
      short8 af = *(const short8*)&h_bf[l15][kb*32 + l4*8];
      #pragma unroll
      for (int ct=0; ct<12; ++ct) acc[ct] = mfma16(af, Bf[ct][kb], acc[ct]);
    }
    #pragma unroll
    for (int ct=0; ct<12; ++ct) {
      int col = w*192 + ct*16 + l15;
      #pragma unroll
      for (int q=0; q<4; ++q) hg[l4*4+q][col] = acc[ct][q];
    }
    __syncthreads();

    // ---- gate phase: each thread owns hidden unit j for all 16 rows ----
    #pragma unroll 4
    for (int i=0; i<16; ++i) {
      long xrow = (long)(rowbase+i)*T + t;
      const unsigned short* xp = xg + xrow*768;
      float xr = bf2f(xp[j]);
      float xz = bf2f(xp[256+j]);
      float xn = bf2f(xp[512+j]);
      float hr = hg[i][j]     + b_r;
      float hz = hg[i][256+j] + b_z;
      float hn = hg[i][512+j] + b_n;
      float r = sigf(xr + hr);
      float z = sigf(xz + hz);
      float n = tanhfast(xn + r*hn);
      float hv = n + z*(h[i] - n);
      if (mask && !mask[xrow]) hv = h[i];
      h[i] = hv;
      h_bf[i][j] = f2bf(hv);
      if (outs) outs[xrow*256 + j] = f2bf(hv);
    }
    __syncthreads();
  }

  if (hN) {
    #pragma unroll
    for (int i=0; i<16; ++i) hN[(long)(rowbase+i)*256 + j] = h[i];
  }
}

// ---------------------------------------------------------------------------
// Memory scan: per batch b (block, 1 wave): 32 steps of attention-write memory.
//   lane owns cols 4l..4l+3 for ALL 16 mem slots -> softmax fully lane-local
//   after a 16-value cross-lane butterfly reduce.
// ---------------------------------------------------------------------------
__global__ __launch_bounds__(64) void k_mem(
    const float* __restrict__ z,         // [512][256] rows b*32+t
    const float* __restrict__ mem_init,  // [16][256]
    float* __restrict__ z2)              // [512][256]
{
  const int b = blockIdx.x;
  const int lane = threadIdx.x;
  float mem[16][4];
  #pragma unroll
  for (int m=0; m<16; ++m) {
    f32x4 v = *(const f32x4*)(mem_init + m*256 + lane*4);
    mem[m][0]=v[0]; mem[m][1]=v[1]; mem[m][2]=v[2]; mem[m][3]=v[3];
  }
  for (int t=0; t<32; ++t) {
    f32x4 q = *(const f32x4*)(z + ((long)b*32 + t)*256 + lane*4);
    float s[16];
    #pragma unroll
    for (int m=0; m<16; ++m)
      s[m] = mem[m][0]*q[0] + mem[m][1]*q[1] + mem[m][2]*q[2] + mem[m][3]*q[3];
    #pragma unroll
    for (int st=1; st<64; st<<=1) {
      #pragma unroll
      for (int m=0; m<16; ++m) s[m] += __shfl_xor(s[m], st, 64);
    }
    float mx = -1e30f;
    #pragma unroll
    for (int m=0; m<16; ++m) { s[m] *= 0.0625f; mx = fmaxf(mx, s[m]); }
    float sum = 0.f;
    #pragma unroll
    for (int m=0; m<16; ++m) { s[m] = __expf(s[m]-mx); sum += s[m]; }
    float inv = 1.f / sum;
    f32x4 ro = {0.f,0.f,0.f,0.f};
    #pragma unroll
    for (int m=0; m<16; ++m) {
      float wm = s[m]*inv;
      #pragma unroll
      for (int c=0; c<4; ++c) {
        ro[c] += wm * mem[m][c];
        mem[m][c] += wm * (q[c] - mem[m][c]);
      }
    }
    f32x4 o = q + ro;
    *(f32x4*)(z2 + ((long)b*32 + t)*256 + lane*4) = o;
  }
}

// ---------------------------------------------------------------------------
// Head GEMM: out[2032][32000] = A[2032][256]bf16 @ Bw[32000][256]^T + bias
//   128x128 tile, K=256 whole. B staged in LDS (xor-swizzled), A direct.
// ---------------------------------------------------------------------------
__global__ __launch_bounds__(256) void k_head(
    const unsigned short* __restrict__ A,    // [2048][256] bf16 (padded)
    const unsigned short* __restrict__ Bw,   // [32000][256] bf16
    const float* __restrict__ bias,          // [32000]
    float* __restrict__ out,                 // [2032][32000]
    int M)
{
  __shared__ unsigned short Bs[32768];       // 64 KB
  const int bid = blockIdx.x;
  const int mt = bid % 16, nt = bid / 16;
  const int tid = threadIdx.x;
  const int lane = tid & 63, w = tid >> 6;
  const int l15 = lane & 15, l4 = lane >> 4;

  // stage B-tile with xor swizzle on 16B chunks (chunk ^ (row&7))
  const long nbase = (long)nt * 128;
  #pragma unroll
  for (int it=0; it<16; ++it) {
    int idx = it*256 + tid;                  // 0..4095 16B-chunks
    int rr = idx >> 5;                       // 0..127
    int ch = idx & 31;
    int sch = ch ^ (rr & 7);
    u32x4 v = *(const u32x4*)(Bw + (nbase+rr)*256 + sch*8);
    *(u32x4*)&Bs[(long)idx*8] = v;
  }
  __syncthreads();

  const int m0 = mt*128 + w*32;
  const int arow0 = m0 + l15, arow1 = arow0 + 16;
  const int kc = l4 * 8;

  f32x4 acc[2][8];
  #pragma unroll
  for (int rt=0; rt<2; ++rt)
    #pragma unroll
    for (int ct=0; ct<8; ++ct){ f32x4 z4={0.f,0.f,0.f,0.f}; acc[rt][ct]=z4; }

  #pragma unroll
  for (int kb=0; kb<8; ++kb) {
    short8 a0 = *(const short8*)(A + (long)arow0*256 + kb*32 + kc);
    short8 a1 = *(const short8*)(A + (long)arow1*256 + kb*32 + kc);
    int c = kb*4 + l4;
    #pragma unroll
    for (int ct=0; ct<8; ++ct) {
      int n_local = ct*16 + l15;
      int sc = c ^ (n_local & 7);
      short8 bf = *(const short8*)&Bs[((long)n_local*32 + sc)*8];
      acc[0][ct] = mfma16(a0, bf, acc[0][ct]);
      acc[1][ct] = mfma16(a1, bf, acc[1][ct]);
    }
  }

  #pragma unroll
  for (int ct=0; ct<8; ++ct) {
    int n_g = nt*128 + ct*16 + l15;
    float bv = bias[n_g];
    #pragma unroll
    for (int rt=0; rt<2; ++rt) {
      #pragma unroll
      for (int q=0; q<4; ++q) {
        int r_g = m0 + rt*16 + l4*4 + q;
        if (r_g < M) out[(long)r_g*32000 + n_g] = acc[rt][ct][q] + bv;
      }
    }
  }
}

// ---------------------------------------------------------------------------
extern "C" void kernel_launch(void* const* d_in, const int* in_sizes, int n_in,
                              void* d_out, int out_size, void* d_ws, size_t ws_size,
                              hipStream_t stream)
{
  (void)in_sizes; (void)n_in; (void)out_size; (void)ws_size;
  const int*   ctx_ids  = (const int*)  d_in[0];
  const int*   ctx_mask = (const int*)  d_in[1];
  const float* img      = (const float*)d_in[2];
  const int*   tgt_ids  = (const int*)  d_in[3];
  const float* emb_text = (const float*)d_in[4];
  const float* Wih_t    = (const float*)d_in[5];
  const float* Whh_t    = (const float*)d_in[6];
  const float* bih_t    = (const float*)d_in[7];
  const float* bhh_t    = (const float*)d_in[8];
  const float* fuse_W   = (const float*)d_in[9];
  const float* fuse_b   = (const float*)d_in[10];
  const float* mem_init = (const float*)d_in[11];
  const float* Wih_c    = (const float*)d_in[12];
  const float* Whh_c    = (const float*)d_in[13];
  const float* bih_c    = (const float*)d_in[14];
  const float* bhh_c    = (const float*)d_in[15];
  const float* tok_emb  = (const float*)d_in[16];
  const float* Wih_d    = (const float*)d_in[17];
  const float* Whh_d    = (const float*)d_in[18];
  const float* bih_d    = (const float*)d_in[19];
  const float* bhh_d    = (const float*)d_in[20];
  const float* head_W   = (const float*)d_in[21];
  const float* head_b   = (const float*)d_in[22];
  float* out = (float*)d_out;
  char* ws = (char*)d_ws;

  size_t o = 0;
  auto alloc = [&](size_t bytes){ size_t r = o; o += (bytes + 255) & ~(size_t)255; return r; };
  unsigned short* wWih_t = (unsigned short*)(ws + alloc(768*256*2));
  unsigned short* wWhh_t = (unsigned short*)(ws + alloc(768*256*2));
  unsigned short* wWih_c = (unsigned short*)(ws + alloc(768*256*2));
  unsigned short* wWhh_c = (unsigned short*)(ws + alloc(768*256*2));
  unsigned short* wWih_d = (unsigned short*)(ws + alloc(768*256*2));
  unsigned short* wWhh_d = (unsigned short*)(ws + alloc(768*256*2));
  unsigned short* wFuse  = (unsigned short*)(ws + alloc(256*768*2));
  unsigned short* wHead  = (unsigned short*)(ws + alloc((size_t)32000*256*2));
  unsigned short* xg_t   = (unsigned short*)(ws + alloc((size_t)16384*768*2));
  unsigned short* xg_c   = (unsigned short*)(ws + alloc((size_t)512*768*2));
  unsigned short* xg_d   = (unsigned short*)(ws + alloc((size_t)2032*768*2));
  float*          tvec   = (float*)(ws + alloc((size_t)512*256*4));
  float*          zbuf   = (float*)(ws + alloc((size_t)512*256*4));
  float*          z2buf  = (float*)(ws + alloc((size_t)512*256*4));
  float*          h0buf  = (float*)(ws + alloc((size_t)16*256*4));
  unsigned short* outsb  = (unsigned short*)(ws + alloc((size_t)2048*256*2));

  // 0) weights -> bf16
  k_cvt<<<2048, 256, 0, stream>>>(head_W, wHead,
      Wih_t, Whh_t, Wih_c, Whh_c, Wih_d, Whh_d, fuse_W,
      wWih_t, wWhh_t, wWih_c, wWhh_c, wWih_d, wWhh_d, wFuse);

  // 1) xg for ctx text GRU: rows = (b*K+k)*L + l = 16384
  k_gemm<32,32,0><<<dim3(256,6), 256, 0, stream>>>(
      emb_text, 256, nullptr, 0, 256, ctx_ids, wWih_t, bih_t, 16384, 256, xg_t, 768);

  // 1b) xg for decoder (independent): rows = b*127 + t = 2032
  k_gemm<127,128,0><<<dim3(32,6), 256, 0, stream>>>(
      tok_emb, 256, nullptr, 0, 256, tgt_ids, wWih_d, bih_d, 2032, 256, xg_d, 768);

  // 2) ctx text GRU (masked), 512 rows -> tvec
  k_gru<<<32, 256, 0, stream>>>(wWhh_t, bhh_t, xg_t, ctx_mask,
                                nullptr, tvec, nullptr, 32);

  // 3) fuse: z = tanh([tvec|img] @ fuse_W^T + fuse_b), 512x256
  k_gemm<1,1,1><<<dim3(8,2), 256, 0, stream>>>(
      tvec, 256, img, 512, 256, nullptr, wFuse, fuse_b, 512, 768, zbuf, 256);

  // 4) memory scan -> z2
  k_mem<<<16, 64, 0, stream>>>(zbuf, mem_init, z2buf);

  // 5) xg for ctx GRU2 from z2 (rows b*32+t = 512)
  k_gemm<1,1,0><<<dim3(8,6), 256, 0, stream>>>(
      z2buf, 256, nullptr, 0, 256, nullptr, wWih_c, bih_c, 512, 256, xg_c, 768);

  // 6) ctx GRU2 -> h0
  k_gru<<<1, 256, 0, stream>>>(wWhh_c, bhh_c, xg_c, nullptr,
                               nullptr, h0buf, nullptr, 32);

  // 7) decoder GRU -> outs (bf16, 2032 rows; rows 2032..2047 of buffer unused)
  k_gru<<<1, 256, 0, stream>>>(wWhh_d, bhh_d, xg_d, nullptr,
                               h0buf, nullptr, outsb, 127);

  // 8) head: logits
  k_head<<<4000, 256, 0, stream>>>(outsb, wHead, head_b, out, 2032);
}

// Round 2
// 874.469 us; speedup vs baseline: 3.1276x; 3.1276x over previous
//
#include <hip/hip_runtime.h>
#include <hip/hip_bf16.h>

typedef __attribute__((ext_vector_type(4))) float f32x4;
typedef __attribute__((ext_vector_type(8))) short short8;
typedef __attribute__((ext_vector_type(4))) unsigned int u32x4;
typedef __attribute__((ext_vector_type(4))) unsigned short u16x4;

static __device__ __forceinline__ unsigned short f2bf(float f){
  unsigned u = __builtin_bit_cast(unsigned, f);
  u += 0x7FFFu + ((u >> 16) & 1u);
  return (unsigned short)(u >> 16);
}
static __device__ __forceinline__ float bf2f(unsigned short b){
  return __builtin_bit_cast(float, ((unsigned)b) << 16);
}
static __device__ __forceinline__ f32x4 mfma16(short8 a, short8 b, f32x4 c){
  return __builtin_amdgcn_mfma_f32_16x16x32_bf16(a, b, c, 0, 0, 0);
}
static __device__ __forceinline__ float rcpf(float x){ return __builtin_amdgcn_rcpf(x); }
static __device__ __forceinline__ float sigf(float x){ return rcpf(1.f + __expf(-x)); }
static __device__ __forceinline__ float tanhfast(float x){
  float e = __expf(2.f*x);
  return (e - 1.f) * rcpf(e + 1.f);
}

// ---------------------------------------------------------------------------
// fp32 -> bf16 weight conversion (head_W + 7 small matrices of 196608 elems)
// ---------------------------------------------------------------------------
__global__ __launch_bounds__(256) void k_cvt(
    const float* __restrict__ sh, unsigned short* __restrict__ dh,
    const float* __restrict__ s0, const float* __restrict__ s1,
    const float* __restrict__ s2, const float* __restrict__ s3,
    const float* __restrict__ s4, const float* __restrict__ s5,
    const float* __restrict__ s6,
    unsigned short* __restrict__ d0, unsigned short* __restrict__ d1,
    unsigned short* __restrict__ d2, unsigned short* __restrict__ d3,
    unsigned short* __restrict__ d4, unsigned short* __restrict__ d5,
    unsigned short* __restrict__ d6)
{
  const long NH4 = 2048000;   // head: 8,192,000 floats / 4
  const long NS4 = 49152;     // small: 196,608 floats / 4
  const long total = NH4 + 7*NS4;
  for (long idx = (long)blockIdx.x*blockDim.x + threadIdx.x; idx < total;
       idx += (long)gridDim.x*blockDim.x) {
    const float* s; unsigned short* d; long off;
    if (idx < NH4) { s = sh; d = dh; off = idx; }
    else {
      long r = idx - NH4; int mat = (int)(r / NS4); off = r - (long)mat*NS4;
      switch (mat) {
        case 0: s=s0; d=d0; break;  case 1: s=s1; d=d1; break;
        case 2: s=s2; d=d2; break;  case 3: s=s3; d=d3; break;
        case 4: s=s4; d=d4; break;  case 5: s=s5; d=d5; break;
        default: s=s6; d=d6; break;
      }
    }
    f32x4 v = ((const f32x4*)s)[off];
    u16x4 o2;
    o2[0]=f2bf(v[0]); o2[1]=f2bf(v[1]); o2[2]=f2bf(v[2]); o2[3]=f2bf(v[3]);
    ((u16x4*)d)[off] = o2;
  }
}

// ---------------------------------------------------------------------------
// Generic MFMA GEMM: out[M][N] = gatherA[M][Ktot] @ W[N][Ktot]^T + bias
// ---------------------------------------------------------------------------
template<int TN, int TS, int EPI>
__global__ __launch_bounds__(256) void k_gemm(
    const float* __restrict__ tabA, int ldA,
    const float* __restrict__ tabB2, int ldB2, int K1,
    const int* __restrict__ ids,
    const unsigned short* __restrict__ W,   // [N][Ktot] bf16
    const float* __restrict__ bias,         // [N]
    int M, int Ktot,
    void* __restrict__ outp, int ldOut)
{
  const int bm = blockIdx.x, bn = blockIdx.y;
  const int tid = threadIdx.x;
  const int lane = tid & 63, w = tid >> 6;
  const int l15 = lane & 15, l4 = lane >> 4;

  const int r_g = bm*64 + w*16 + l15;
  const int r_c = (r_g < M) ? r_g : (M-1);
  long row_src;
  if (ids) { int ii = (r_c / TN) * TS + (r_c % TN); row_src = ids[ii]; }
  else row_src = r_c;

  const int kchunk = l4 * 8;
  const int ncol0 = bn*128 + l15;

  f32x4 acc[8];
  #pragma unroll
  for (int i=0;i<8;i++){ f32x4 z4 = {0.f,0.f,0.f,0.f}; acc[i]=z4; }

  const int KB = Ktot >> 5;
  for (int kb = 0; kb < KB; ++kb) {
    int k = kb*32 + kchunk;
    const float* ap;
    if (tabB2 && k >= K1) ap = tabB2 + row_src*(long)ldB2 + (k - K1);
    else                  ap = tabA  + row_src*(long)ldA  + k;
    f32x4 a0 = *(const f32x4*)ap;
    f32x4 a1 = *(const f32x4*)(ap + 4);
    short8 afr;
    afr[0]=(short)f2bf(a0[0]); afr[1]=(short)f2bf(a0[1]);
    afr[2]=(short)f2bf(a0[2]); afr[3]=(short)f2bf(a0[3]);
    afr[4]=(short)f2bf(a1[0]); afr[5]=(short)f2bf(a1[1]);
    afr[6]=(short)f2bf(a1[2]); afr[7]=(short)f2bf(a1[3]);
    #pragma unroll
    for (int ct=0; ct<8; ++ct) {
      int n = ncol0 + ct*16;
      short8 bfr = *(const short8*)(W + (long)n*Ktot + k);
      acc[ct] = mfma16(afr, bfr, acc[ct]);
    }
  }

  #pragma unroll
  for (int ct=0; ct<8; ++ct) {
    int n = ncol0 + ct*16;
    float bv = bias[n];
    #pragma unroll
    for (int q=0; q<4; ++q) {
      int rr = bm*64 + w*16 + l4*4 + q;
      if (rr < M) {
        float v = acc[ct][q] + bv;
        if (EPI == 1) ((float*)outp)[(long)rr*ldOut + n] = tanhfast(v);
        else ((unsigned short*)outp)[(long)rr*ldOut + n] = f2bf(v);
      }
    }
  }
}

// ---------------------------------------------------------------------------
// GRU recurrence, 512 threads / 8 waves, 16 rows per block.
//   Whh split: per wave 6 col-tiles of 16 -> 1 in LDS + 5 in registers
//   (160 VGPR frags; total ~235 VGPR, fits the 256 cap at 2 waves/SIMD).
//   bhh folded into hg at MFMA write-out.
//   Gate phase: thread owns (row gi, units gj..gj+7) -> all vector accesses.
// ---------------------------------------------------------------------------
__global__ __launch_bounds__(512, 2) void k_gru(
    const unsigned short* __restrict__ Whh,  // [768][256] bf16
    const float* __restrict__ bhh,           // [768]
    const unsigned short* __restrict__ xg,   // [(grow*T+t)][768] bf16 (bih included)
    const int* __restrict__ mask,            // [(grow*T+t)] or null
    const float* __restrict__ h0,            // [R][256] or null
    float* __restrict__ hN,                  // [R][256] or null
    unsigned short* __restrict__ outs,       // [(grow*T+t)][256] bf16 or null
    int T)
{
  __shared__ unsigned short h_bf[16][264];       // 528B row stride (2-way max)
  __shared__ float hg[16][772];                  // +4 f32 pad
  __shared__ unsigned short Wlds[8*8*64*8];      // [w][kb][lane] x short8 = 64KB

  const int tid = threadIdx.x;
  const int lane = tid & 63;
  const int w = tid >> 6;                        // 0..7
  const int l15 = lane & 15, l4 = lane >> 4;
  const int rowbase = blockIdx.x * 16;
  const int n0 = w*96 + l15;

  // ---- preload Whh: col-tile 0 -> LDS, tiles 1..5 -> registers ----
  #pragma unroll
  for (int kb=0; kb<8; ++kb)
    *(short8*)&Wlds[(((w*8+kb)*64) + lane)*8] =
        *(const short8*)(Whh + (long)n0*256 + kb*32 + l4*8);
  short8 Bf[5][8];
  #pragma unroll
  for (int ct=0; ct<5; ++ct)
    #pragma unroll
    for (int kb=0; kb<8; ++kb)
      Bf[ct][kb] = *(const short8*)(Whh + (long)(n0 + (ct+1)*16)*256 + kb*32 + l4*8);

  float bias6[6];
  #pragma unroll
  for (int ct=0; ct<6; ++ct) bias6[ct] = bhh[w*96 + ct*16 + l15];

  // ---- gate-phase mapping: row gi, unit base gj ----
  const int gi = tid & 15;
  const int gj = (tid >> 4) * 8;
  float h[8];
  {
    float hv[8];
    if (h0) {
      f32x4 a = *(const f32x4*)(h0 + (long)(rowbase+gi)*256 + gj);
      f32x4 b = *(const f32x4*)(h0 + (long)(rowbase+gi)*256 + gj + 4);
      hv[0]=a[0];hv[1]=a[1];hv[2]=a[2];hv[3]=a[3];
      hv[4]=b[0];hv[5]=b[1];hv[6]=b[2];hv[7]=b[3];
    } else {
      #pragma unroll
      for (int q=0;q<8;++q) hv[q]=0.f;
    }
    short8 hb;
    #pragma unroll
    for (int q=0;q<8;++q) { h[q]=hv[q]; hb[q]=(short)f2bf(hv[q]); }
    *(short8*)&h_bf[gi][gj] = hb;
  }
  __syncthreads();

  for (int t=0; t<T; ++t) {
    // ---- MFMA phase: hg = h @ Whh^T + bhh ----
    f32x4 acc[6];
    #pragma unroll
    for (int ct=0; ct<6; ++ct){ f32x4 z4={0.f,0.f,0.f,0.f}; acc[ct]=z4; }
    #pragma unroll
    for (int kb=0; kb<8; ++kb) {
      short8 af = *(const short8*)&h_bf[l15][kb*32 + l4*8];
      short8 b0 = *(const short8*)&Wlds[(((w*8+kb)*64) + lane)*8];
      acc[0] = mfma16(af, b0, acc[0]);
      #pragma unroll
      for (int ct=0; ct<5; ++ct) acc[ct+1] = mfma16(af, Bf[ct][kb], acc[ct+1]);
    }
    #pragma unroll
    for (int ct=0; ct<6; ++ct) {
      int col = w*96 + ct*16 + l15;
      float bv = bias6[ct];
      #pragma unroll
      for (int q=0; q<4; ++q) hg[l4*4+q][col] = acc[ct][q] + bv;
    }
    __syncthreads();

    // ---- gate phase ----
    const long xrow = (long)(rowbase+gi)*T + t;
    const unsigned short* xp = xg + xrow*768;
    short8 xrv = *(const short8*)(xp + gj);
    short8 xzv = *(const short8*)(xp + 256 + gj);
    short8 xnv = *(const short8*)(xp + 512 + gj);
    float hrv[8], hzv[8], hnv[8];
    *(f32x4*)&hrv[0] = *(const f32x4*)&hg[gi][gj];
    *(f32x4*)&hrv[4] = *(const f32x4*)&hg[gi][gj+4];
    *(f32x4*)&hzv[0] = *(const f32x4*)&hg[gi][256+gj];
    *(f32x4*)&hzv[4] = *(const f32x4*)&hg[gi][256+gj+4];
    *(f32x4*)&hnv[0] = *(const f32x4*)&hg[gi][512+gj];
    *(f32x4*)&hnv[4] = *(const f32x4*)&hg[gi][512+gj+4];
    const int mok = mask ? mask[xrow] : 1;
    short8 hb;
    #pragma unroll
    for (int q=0; q<8; ++q) {
      float xr = bf2f((unsigned short)xrv[q]);
      float xz = bf2f((unsigned short)xzv[q]);
      float xn = bf2f((unsigned short)xnv[q]);
      float r = sigf(xr + hrv[q]);
      float z = sigf(xz + hzv[q]);
      float n = tanhfast(xn + r*hnv[q]);
      float hv = n + z*(h[q] - n);
      if (!mok) hv = h[q];
      h[q] = hv;
      hb[q] = (short)f2bf(hv);
    }
    *(short8*)&h_bf[gi][gj] = hb;
    if (outs) *(short8*)(outs + xrow*256 + gj) = hb;
    __syncthreads();
  }

  if (hN) {
    f32x4 a = { h[0], h[1], h[2], h[3] };
    f32x4 b = { h[4], h[5], h[6], h[7] };
    *(f32x4*)(hN + (long)(rowbase+gi)*256 + gj)     = a;
    *(f32x4*)(hN + (long)(rowbase+gi)*256 + gj + 4) = b;
  }
}

// ---------------------------------------------------------------------------
// Memory scan: per batch b (block, 1 wave): 32 steps of attention-write memory.
// ---------------------------------------------------------------------------
__global__ __launch_bounds__(64) void k_mem(
    const float* __restrict__ z,         // [512][256] rows b*32+t
    const float* __restrict__ mem_init,  // [16][256]
    float* __restrict__ z2)              // [512][256]
{
  const int b = blockIdx.x;
  const int lane = threadIdx.x;
  float mem[16][4];
  #pragma unroll
  for (int m=0; m<16; ++m) {
    f32x4 v = *(const f32x4*)(mem_init + m*256 + lane*4);
    mem[m][0]=v[0]; mem[m][1]=v[1]; mem[m][2]=v[2]; mem[m][3]=v[3];
  }
  for (int t=0; t<32; ++t) {
    f32x4 q = *(const f32x4*)(z + ((long)b*32 + t)*256 + lane*4);
    float s[16];
    #pragma unroll
    for (int m=0; m<16; ++m)
      s[m] = mem[m][0]*q[0] + mem[m][1]*q[1] + mem[m][2]*q[2] + mem[m][3]*q[3];
    #pragma unroll
    for (int st=1; st<64; st<<=1) {
      #pragma unroll
      for (int m=0; m<16; ++m) s[m] += __shfl_xor(s[m], st, 64);
    }
    float mx = -1e30f;
    #pragma unroll
    for (int m=0; m<16; ++m) { s[m] *= 0.0625f; mx = fmaxf(mx, s[m]); }
    float sum = 0.f;
    #pragma unroll
    for (int m=0; m<16; ++m) { s[m] = __expf(s[m]-mx); sum += s[m]; }
    float inv = rcpf(sum);
    f32x4 ro = {0.f,0.f,0.f,0.f};
    #pragma unroll
    for (int m=0; m<16; ++m) {
      float wm = s[m]*inv;
      #pragma unroll
      for (int c=0; c<4; ++c) {
        ro[c] += wm * mem[m][c];
        mem[m][c] += wm * (q[c] - mem[m][c]);
      }
    }
    f32x4 o = q + ro;
    *(f32x4*)(z2 + ((long)b*32 + t)*256 + lane*4) = o;
  }
}

// ---------------------------------------------------------------------------
// Head GEMM: out[2032][32000] = A[2032][256]bf16 @ Bw[32000][256]^T + bias
// ---------------------------------------------------------------------------
__global__ __launch_bounds__(256) void k_head(
    const unsigned short* __restrict__ A,    // [2048][256] bf16 (padded)
    const unsigned short* __restrict__ Bw,   // [32000][256] bf16
    const float* __restrict__ bias,          // [32000]
    float* __restrict__ out,                 // [2032][32000]
    int M)
{
  __shared__ unsigned short Bs[32768];       // 64 KB
  const int bid = blockIdx.x;
  const int mt = bid % 16, nt = bid / 16;
  const int tid = threadIdx.x;
  const int lane = tid & 63, w = tid >> 6;
  const int l15 = lane & 15, l4 = lane >> 4;

  const long nbase = (long)nt * 128;
  #pragma unroll
  for (int it=0; it<16; ++it) {
    int idx = it*256 + tid;                  // 0..4095 16B-chunks
    int rr = idx >> 5;                       // 0..127
    int ch = idx & 31;
    int sch = ch ^ (rr & 7);
    u32x4 v = *(const u32x4*)(Bw + (nbase+rr)*256 + sch*8);
    *(u32x4*)&Bs[(long)idx*8] = v;
  }
  __syncthreads();

  const int m0 = mt*128 + w*32;
  const int arow0 = m0 + l15, arow1 = arow0 + 16;
  const int kc = l4 * 8;

  f32x4 acc[2][8];
  #pragma unroll
  for (int rt=0; rt<2; ++rt)
    #pragma unroll
    for (int ct=0; ct<8; ++ct){ f32x4 z4={0.f,0.f,0.f,0.f}; acc[rt][ct]=z4; }

  #pragma unroll
  for (int kb=0; kb<8; ++kb) {
    short8 a0 = *(const short8*)(A + (long)arow0*256 + kb*32 + kc);
    short8 a1 = *(const short8*)(A + (long)arow1*256 + kb*32 + kc);
    int c = kb*4 + l4;
    #pragma unroll
    for (int ct=0; ct<8; ++ct) {
      int n_local = ct*16 + l15;
      int sc = c ^ (n_local & 7);
      short8 bf = *(const short8*)&Bs[((long)n_local*32 + sc)*8];
      acc[0][ct] = mfma16(a0, bf, acc[0][ct]);
      acc[1][ct] = mfma16(a1, bf, acc[1][ct]);
    }
  }

  #pragma unroll
  for (int ct=0; ct<8; ++ct) {
    int n_g = nt*128 + ct*16 + l15;
    float bv = bias[n_g];
    #pragma unroll
    for (int rt=0; rt<2; ++rt) {
      #pragma unroll
      for (int q=0; q<4; ++q) {
        int r_g = m0 + rt*16 + l4*4 + q;
        if (r_g < M) out[(long)r_g*32000 + n_g] = acc[rt][ct][q] + bv;
      }
    }
  }
}

// ---------------------------------------------------------------------------
extern "C" void kernel_launch(void* const* d_in, const int* in_sizes, int n_in,
                              void* d_out, int out_size, void* d_ws, size_t ws_size,
                              hipStream_t stream)
{
  (void)in_sizes; (void)n_in; (void)out_size; (void)ws_size;
  const int*   ctx_ids  = (const int*)  d_in[0];
  const int*   ctx_mask = (const int*)  d_in[1];
  const float* img      = (const float*)d_in[2];
  const int*   tgt_ids  = (const int*)  d_in[3];
  const float* emb_text = (const float*)d_in[4];
  const float* Wih_t    = (const float*)d_in[5];
  const float* Whh_t    = (const float*)d_in[6];
  const float* bih_t    = (const float*)d_in[7];
  const float* bhh_t    = (const float*)d_in[8];
  const float* fuse_W   = (const float*)d_in[9];
  const float* fuse_b   = (const float*)d_in[10];
  const float* mem_init = (const float*)d_in[11];
  const float* Wih_c    = (const float*)d_in[12];
  const float* Whh_c    = (const float*)d_in[13];
  const float* bih_c    = (const float*)d_in[14];
  const float* bhh_c    = (const float*)d_in[15];
  const float* tok_emb  = (const float*)d_in[16];
  const float* Wih_d    = (const float*)d_in[17];
  const float* Whh_d    = (const float*)d_in[18];
  const float* bih_d    = (const float*)d_in[19];
  const float* bhh_d    = (const float*)d_in[20];
  const float* head_W   = (const float*)d_in[21];
  const float* head_b   = (const float*)d_in[22];
  float* out = (float*)d_out;
  char* ws = (char*)d_ws;

  size_t o = 0;
  auto alloc = [&](size_t bytes){ size_t r = o; o += (bytes + 255) & ~(size_t)255; return r; };
  unsigned short* wWih_t = (unsigned short*)(ws + alloc(768*256*2));
  unsigned short* wWhh_t = (unsigned short*)(ws + alloc(768*256*2));
  unsigned short* wWih_c = (unsigned short*)(ws + alloc(768*256*2));
  unsigned short* wWhh_c = (unsigned short*)(ws + alloc(768*256*2));
  unsigned short* wWih_d = (unsigned short*)(ws + alloc(768*256*2));
  unsigned short* wWhh_d = (unsigned short*)(ws + alloc(768*256*2));
  unsigned short* wFuse  = (unsigned short*)(ws + alloc(256*768*2));
  unsigned short* wHead  = (unsigned short*)(ws + alloc((size_t)32000*256*2));
  unsigned short* xg_t   = (unsigned short*)(ws + alloc((size_t)16384*768*2));
  unsigned short* xg_c   = (unsigned short*)(ws + alloc((size_t)512*768*2));
  unsigned short* xg_d   = (unsigned short*)(ws + alloc((size_t)2032*768*2));
  float*          tvec   = (float*)(ws + alloc((size_t)512*256*4));
  float*          zbuf   = (float*)(ws + alloc((size_t)512*256*4));
  float*          z2buf  = (float*)(ws + alloc((size_t)512*256*4));
  float*          h0buf  = (float*)(ws + alloc((size_t)16*256*4));
  unsigned short* outsb  = (unsigned short*)(ws + alloc((size_t)2048*256*2));

  // 0) weights -> bf16
  k_cvt<<<2048, 256, 0, stream>>>(head_W, wHead,
      Wih_t, Whh_t, Wih_c, Whh_c, Wih_d, Whh_d, fuse_W,
      wWih_t, wWhh_t, wWih_c, wWhh_c, wWih_d, wWhh_d, wFuse);

  // 1) xg for ctx text GRU: rows = (b*K+k)*L + l = 16384
  k_gemm<32,32,0><<<dim3(256,6), 256, 0, stream>>>(
      emb_text, 256, nullptr, 0, 256, ctx_ids, wWih_t, bih_t, 16384, 256, xg_t, 768);

  // 1b) xg for decoder (independent): rows = b*127 + t = 2032
  k_gemm<127,128,0><<<dim3(32,6), 256, 0, stream>>>(
      tok_emb, 256, nullptr, 0, 256, tgt_ids, wWih_d, bih_d, 2032, 256, xg_d, 768);

  // 2) ctx text GRU (masked), 512 rows -> tvec
  k_gru<<<32, 512, 0, stream>>>(wWhh_t, bhh_t, xg_t, ctx_mask,
                                nullptr, tvec, nullptr, 32);

  // 3) fuse: z = tanh([tvec|img] @ fuse_W^T + fuse_b), 512x256
  k_gemm<1,1,1><<<dim3(8,2), 256, 0, stream>>>(
      tvec, 256, img, 512, 256, nullptr, wFuse, fuse_b, 512, 768, zbuf, 256);

  // 4) memory scan -> z2
  k_mem<<<16, 64, 0, stream>>>(zbuf, mem_init, z2buf);

  // 5) xg for ctx GRU2 from z2 (rows b*32+t = 512)
  k_gemm<1,1,0><<<dim3(8,6), 256, 0, stream>>>(
      z2buf, 256, nullptr, 0, 256, nullptr, wWih_c, bih_c, 512, 256, xg_c, 768);

  // 6) ctx GRU2 -> h0
  k_gru<<<1, 512, 0, stream>>>(wWhh_c, bhh_c, xg_c, nullptr,
                               nullptr, h0buf, nullptr, 32);

  // 7) decoder GRU -> outs (bf16, 2032 rows)
  k_gru<<<1, 512, 0, stream>>>(wWhh_d, bhh_d, xg_d, nullptr,
                               h0buf, nullptr, outsb, 127);

  // 8) head: logits
  k_head<<<4000, 256, 0, stream>>>(outsb, wHead, head_b, out, 2032);
}

// Round 3
// 849.633 us; speedup vs baseline: 3.2190x; 1.0292x over previous
//
#include <hip/hip_runtime.h>
#include <hip/hip_bf16.h>

typedef __attribute__((ext_vector_type(4))) float f32x4;
typedef __attribute__((ext_vector_type(8))) short short8;
typedef __attribute__((ext_vector_type(4))) unsigned int u32x4;
typedef __attribute__((ext_vector_type(4))) unsigned short u16x4;

static __device__ __forceinline__ unsigned short f2bf(float f){
  unsigned u = __builtin_bit_cast(unsigned, f);
  u += 0x7FFFu + ((u >> 16) & 1u);
  return (unsigned short)(u >> 16);
}
static __device__ __forceinline__ float bf2f(unsigned short b){
  return __builtin_bit_cast(float, ((unsigned)b) << 16);
}
static __device__ __forceinline__ f32x4 mfma16(short8 a, short8 b, f32x4 c){
  return __builtin_amdgcn_mfma_f32_16x16x32_bf16(a, b, c, 0, 0, 0);
}
static __device__ __forceinline__ float rcpf(float x){ return __builtin_amdgcn_rcpf(x); }
static __device__ __forceinline__ float sigf(float x){ return rcpf(1.f + __expf(-x)); }
static __device__ __forceinline__ float tanhfast(float x){
  float e = __expf(2.f*x);
  return (e - 1.f) * rcpf(e + 1.f);
}

// ---------------------------------------------------------------------------
// fp32 -> bf16 weight conversion (head_W + 7 small matrices of 196608 elems)
// ---------------------------------------------------------------------------
__global__ __launch_bounds__(256) void k_cvt(
    const float* __restrict__ sh, unsigned short* __restrict__ dh,
    const float* __restrict__ s0, const float* __restrict__ s1,
    const float* __restrict__ s2, const float* __restrict__ s3,
    const float* __restrict__ s4, const float* __restrict__ s5,
    const float* __restrict__ s6,
    unsigned short* __restrict__ d0, unsigned short* __restrict__ d1,
    unsigned short* __restrict__ d2, unsigned short* __restrict__ d3,
    unsigned short* __restrict__ d4, unsigned short* __restrict__ d5,
    unsigned short* __restrict__ d6)
{
  const long NH4 = 2048000;   // head: 8,192,000 floats / 4
  const long NS4 = 49152;     // small: 196,608 floats / 4
  const long total = NH4 + 7*NS4;
  for (long idx = (long)blockIdx.x*blockDim.x + threadIdx.x; idx < total;
       idx += (long)gridDim.x*blockDim.x) {
    const float* s; unsigned short* d; long off;
    if (idx < NH4) { s = sh; d = dh; off = idx; }
    else {
      long r = idx - NH4; int mat = (int)(r / NS4); off = r - (long)mat*NS4;
      switch (mat) {
        case 0: s=s0; d=d0; break;  case 1: s=s1; d=d1; break;
        case 2: s=s2; d=d2; break;  case 3: s=s3; d=d3; break;
        case 4: s=s4; d=d4; break;  case 5: s=s5; d=d5; break;
        default: s=s6; d=d6; break;
      }
    }
    f32x4 v = ((const f32x4*)s)[off];
    u16x4 o2;
    o2[0]=f2bf(v[0]); o2[1]=f2bf(v[1]); o2[2]=f2bf(v[2]); o2[3]=f2bf(v[3]);
    ((u16x4*)d)[off] = o2;
  }
}

// ---------------------------------------------------------------------------
// Generic MFMA GEMM: out[M][N] = gatherA[M][Ktot] @ W[N][Ktot]^T + bias
// ---------------------------------------------------------------------------
template<int TN, int TS, int EPI>
__global__ __launch_bounds__(256) void k_gemm(
    const float* __restrict__ tabA, int ldA,
    const float* __restrict__ tabB2, int ldB2, int K1,
    const int* __restrict__ ids,
    const unsigned short* __restrict__ W,   // [N][Ktot] bf16
    const float* __restrict__ bias,         // [N]
    int M, int Ktot,
    void* __restrict__ outp, int ldOut)
{
  const int bm = blockIdx.x, bn = blockIdx.y;
  const int tid = threadIdx.x;
  const int lane = tid & 63, w = tid >> 6;
  const int l15 = lane & 15, l4 = lane >> 4;

  const int r_g = bm*64 + w*16 + l15;
  const int r_c = (r_g < M) ? r_g : (M-1);
  long row_src;
  if (ids) { int ii = (r_c / TN) * TS + (r_c % TN); row_src = ids[ii]; }
  else row_src = r_c;

  const int kchunk = l4 * 8;
  const int ncol0 = bn*128 + l15;

  f32x4 acc[8];
  #pragma unroll
  for (int i=0;i<8;i++){ f32x4 z4 = {0.f,0.f,0.f,0.f}; acc[i]=z4; }

  const int KB = Ktot >> 5;
  for (int kb = 0; kb < KB; ++kb) {
    int k = kb*32 + kchunk;
    const float* ap;
    if (tabB2 && k >= K1) ap = tabB2 + row_src*(long)ldB2 + (k - K1);
    else                  ap = tabA  + row_src*(long)ldA  + k;
    f32x4 a0 = *(const f32x4*)ap;
    f32x4 a1 = *(const f32x4*)(ap + 4);
    short8 afr;
    afr[0]=(short)f2bf(a0[0]); afr[1]=(short)f2bf(a0[1]);
    afr[2]=(short)f2bf(a0[2]); afr[3]=(short)f2bf(a0[3]);
    afr[4]=(short)f2bf(a1[0]); afr[5]=(short)f2bf(a1[1]);
    afr[6]=(short)f2bf(a1[2]); afr[7]=(short)f2bf(a1[3]);
    #pragma unroll
    for (int ct=0; ct<8; ++ct) {
      int n = ncol0 + ct*16;
      short8 bfr = *(const short8*)(W + (long)n*Ktot + k);
      acc[ct] = mfma16(afr, bfr, acc[ct]);
    }
  }

  #pragma unroll
  for (int ct=0; ct<8; ++ct) {
    int n = ncol0 + ct*16;
    float bv = bias[n];
    #pragma unroll
    for (int q=0; q<4; ++q) {
      int rr = bm*64 + w*16 + l4*4 + q;
      if (rr < M) {
        float v = acc[ct][q] + bv;
        if (EPI == 1) ((float*)outp)[(long)rr*ldOut + n] = tanhfast(v);
        else ((unsigned short*)outp)[(long)rr*ldOut + n] = f2bf(v);
      }
    }
  }
}

// ---------------------------------------------------------------------------
// GRU recurrence, 512 threads / 8 waves, 16 rows per block.
//   Whh per wave: 6 col-tiles of 16 -> 1 in LDS + 5 pinned in registers.
//   The asm volatile "+v" pin makes the loaded fragments non-rematerializable
//   (round-2 compiler silently re-streamed them from L2 every step: VGPR=120).
//   xg prefetched at loop top so L2 latency hides under the MFMA phase.
// ---------------------------------------------------------------------------
__global__ __launch_bounds__(512, 2) void k_gru(
    const unsigned short* __restrict__ Whh,  // [768][256] bf16
    const float* __restrict__ bhh,           // [768]
    const unsigned short* __restrict__ xg,   // [(grow*T+t)][768] bf16 (bih included)
    const int* __restrict__ mask,            // [(grow*T+t)] or null
    const float* __restrict__ h0,            // [R][256] or null
    float* __restrict__ hN,                  // [R][256] or null
    unsigned short* __restrict__ outs,       // [(grow*T+t)][256] bf16 or null
    int T)
{
  __shared__ unsigned short h_bf[16][264];       // 528B row stride
  __shared__ float hg[16][772];                  // +4 f32 pad
  __shared__ unsigned short Wlds[8*8*64*8];      // [w][kb][lane] x short8 = 64KB

  const int tid = threadIdx.x;
  const int lane = tid & 63;
  const int w = tid >> 6;                        // 0..7
  const int l15 = lane & 15, l4 = lane >> 4;
  const int rowbase = blockIdx.x * 16;
  const int n0 = w*96 + l15;

  // ---- preload Whh: col-tile 0 -> LDS, tiles 1..5 -> pinned registers ----
  #pragma unroll
  for (int kb=0; kb<8; ++kb)
    *(short8*)&Wlds[(((w*8+kb)*64) + lane)*8] =
        *(const short8*)(Whh + (long)n0*256 + kb*32 + l4*8);
  short8 Bf[5][8];
  #pragma unroll
  for (int ct=0; ct<5; ++ct)
    #pragma unroll
    for (int kb=0; kb<8; ++kb) {
      short8 v = *(const short8*)(Whh + (long)(n0 + (ct+1)*16)*256 + kb*32 + l4*8);
      asm volatile("" : "+v"(v));   // pin: not rematerializable
      Bf[ct][kb] = v;
    }

  float bias6[6];
  #pragma unroll
  for (int ct=0; ct<6; ++ct) bias6[ct] = bhh[w*96 + ct*16 + l15];

  // ---- gate-phase mapping: row gi, unit base gj ----
  const int gi = tid & 15;
  const int gj = (tid >> 4) * 8;
  float h[8];
  {
    float hv[8];
    if (h0) {
      f32x4 a = *(const f32x4*)(h0 + (long)(rowbase+gi)*256 + gj);
      f32x4 b = *(const f32x4*)(h0 + (long)(rowbase+gi)*256 + gj + 4);
      hv[0]=a[0];hv[1]=a[1];hv[2]=a[2];hv[3]=a[3];
      hv[4]=b[0];hv[5]=b[1];hv[6]=b[2];hv[7]=b[3];
    } else {
      #pragma unroll
      for (int q=0;q<8;++q) hv[q]=0.f;
    }
    short8 hb;
    #pragma unroll
    for (int q=0;q<8;++q) { h[q]=hv[q]; hb[q]=(short)f2bf(hv[q]); }
    *(short8*)&h_bf[gi][gj] = hb;
  }
  __syncthreads();

  for (int t=0; t<T; ++t) {
    // ---- prefetch this step's x-gates (independent of h) ----
    const long xrow = (long)(rowbase+gi)*T + t;
    const unsigned short* xp = xg + xrow*768;
    short8 xrv = *(const short8*)(xp + gj);
    short8 xzv = *(const short8*)(xp + 256 + gj);
    short8 xnv = *(const short8*)(xp + 512 + gj);
    const int mok = mask ? mask[xrow] : 1;

    // ---- MFMA phase: hg = h @ Whh^T + bhh ----
    f32x4 acc[6];
    #pragma unroll
    for (int ct=0; ct<6; ++ct){ f32x4 z4={0.f,0.f,0.f,0.f}; acc[ct]=z4; }
    #pragma unroll
    for (int kb=0; kb<8; ++kb) {
      short8 af = *(const short8*)&h_bf[l15][kb*32 + l4*8];
      short8 b0 = *(const short8*)&Wlds[(((w*8+kb)*64) + lane)*8];
      acc[0] = mfma16(af, b0, acc[0]);
      #pragma unroll
      for (int ct=0; ct<5; ++ct) acc[ct+1] = mfma16(af, Bf[ct][kb], acc[ct+1]);
    }
    #pragma unroll
    for (int ct=0; ct<6; ++ct) {
      int col = w*96 + ct*16 + l15;
      float bv = bias6[ct];
      #pragma unroll
      for (int q=0; q<4; ++q) hg[l4*4+q][col] = acc[ct][q] + bv;
    }
    __syncthreads();

    // ---- gate phase ----
    float hrv[8], hzv[8], hnv[8];
    *(f32x4*)&hrv[0] = *(const f32x4*)&hg[gi][gj];
    *(f32x4*)&hrv[4] = *(const f32x4*)&hg[gi][gj+4];
    *(f32x4*)&hzv[0] = *(const f32x4*)&hg[gi][256+gj];
    *(f32x4*)&hzv[4] = *(const f32x4*)&hg[gi][256+gj+4];
    *(f32x4*)&hnv[0] = *(const f32x4*)&hg[gi][512+gj];
    *(f32x4*)&hnv[4] = *(const f32x4*)&hg[gi][512+gj+4];
    short8 hb;
    #pragma unroll
    for (int q=0; q<8; ++q) {
      float xr = bf2f((unsigned short)xrv[q]);
      float xz = bf2f((unsigned short)xzv[q]);
      float xn = bf2f((unsigned short)xnv[q]);
      float r = sigf(xr + hrv[q]);
      float z = sigf(xz + hzv[q]);
      float n = tanhfast(xn + r*hnv[q]);
      float hv = n + z*(h[q] - n);
      if (!mok) hv = h[q];
      h[q] = hv;
      hb[q] = (short)f2bf(hv);
    }
    *(short8*)&h_bf[gi][gj] = hb;
    if (outs) *(short8*)(outs + xrow*256 + gj) = hb;
    __syncthreads();
  }

  if (hN) {
    f32x4 a = { h[0], h[1], h[2], h[3] };
    f32x4 b = { h[4], h[5], h[6], h[7] };
    *(f32x4*)(hN + (long)(rowbase+gi)*256 + gj)     = a;
    *(f32x4*)(hN + (long)(rowbase+gi)*256 + gj + 4) = b;
  }
}

// ---------------------------------------------------------------------------
// Memory scan: per batch b (block, 1 wave): 32 steps of attention-write memory.
// ---------------------------------------------------------------------------
__global__ __launch_bounds__(64) void k_mem(
    const float* __restrict__ z,         // [512][256] rows b*32+t
    const float* __restrict__ mem_init,  // [16][256]
    float* __restrict__ z2)              // [512][256]
{
  const int b = blockIdx.x;
  const int lane = threadIdx.x;
  float mem[16][4];
  #pragma unroll
  for (int m=0; m<16; ++m) {
    f32x4 v = *(const f32x4*)(mem_init + m*256 + lane*4);
    mem[m][0]=v[0]; mem[m][1]=v[1]; mem[m][2]=v[2]; mem[m][3]=v[3];
  }
  for (int t=0; t<32; ++t) {
    f32x4 q = *(const f32x4*)(z + ((long)b*32 + t)*256 + lane*4);
    float s[16];
    #pragma unroll
    for (int m=0; m<16; ++m)
      s[m] = mem[m][0]*q[0] + mem[m][1]*q[1] + mem[m][2]*q[2] + mem[m][3]*q[3];
    #pragma unroll
    for (int st=1; st<64; st<<=1) {
      #pragma unroll
      for (int m=0; m<16; ++m) s[m] += __shfl_xor(s[m], st, 64);
    }
    float mx = -1e30f;
    #pragma unroll
    for (int m=0; m<16; ++m) { s[m] *= 0.0625f; mx = fmaxf(mx, s[m]); }
    float sum = 0.f;
    #pragma unroll
    for (int m=0; m<16; ++m) { s[m] = __expf(s[m]-mx); sum += s[m]; }
    float inv = rcpf(sum);
    f32x4 ro = {0.f,0.f,0.f,0.f};
    #pragma unroll
    for (int m=0; m<16; ++m) {
      float wm = s[m]*inv;
      #pragma unroll
      for (int c=0; c<4; ++c) {
        ro[c] += wm * mem[m][c];
        mem[m][c] += wm * (q[c] - mem[m][c]);
      }
    }
    f32x4 o = q + ro;
    *(f32x4*)(z2 + ((long)b*32 + t)*256 + lane*4) = o;
  }
}

// ---------------------------------------------------------------------------
// Head GEMM: out[2032][32000] = A[2032][256]bf16 @ Bw[32000][256]^T + bias
// ---------------------------------------------------------------------------
__global__ __launch_bounds__(256) void k_head(
    const unsigned short* __restrict__ A,    // [2048][256] bf16 (padded)
    const unsigned short* __restrict__ Bw,   // [32000][256] bf16
    const float* __restrict__ bias,          // [32000]
    float* __restrict__ out,                 // [2032][32000]
    int M)
{
  __shared__ unsigned short Bs[32768];       // 64 KB
  const int bid = blockIdx.x;
  const int mt = bid % 16, nt = bid / 16;
  const int tid = threadIdx.x;
  const int lane = tid & 63, w = tid >> 6;
  const int l15 = lane & 15, l4 = lane >> 4;

  const long nbase = (long)nt * 128;
  #pragma unroll
  for (int it=0; it<16; ++it) {
    int idx = it*256 + tid;                  // 0..4095 16B-chunks
    int rr = idx >> 5;                       // 0..127
    int ch = idx & 31;
    int sch = ch ^ (rr & 7);
    u32x4 v = *(const u32x4*)(Bw + (nbase+rr)*256 + sch*8);
    *(u32x4*)&Bs[(long)idx*8] = v;
  }
  __syncthreads();

  const int m0 = mt*128 + w*32;
  const int arow0 = m0 + l15, arow1 = arow0 + 16;
  const int kc = l4 * 8;

  f32x4 acc[2][8];
  #pragma unroll
  for (int rt=0; rt<2; ++rt)
    #pragma unroll
    for (int ct=0; ct<8; ++ct){ f32x4 z4={0.f,0.f,0.f,0.f}; acc[rt][ct]=z4; }

  #pragma unroll
  for (int kb=0; kb<8; ++kb) {
    short8 a0 = *(const short8*)(A + (long)arow0*256 + kb*32 + kc);
    short8 a1 = *(const short8*)(A + (long)arow1*256 + kb*32 + kc);
    int c = kb*4 + l4;
    #pragma unroll
    for (int ct=0; ct<8; ++ct) {
      int n_local = ct*16 + l15;
      int sc = c ^ (n_local & 7);
      short8 bf = *(const short8*)&Bs[((long)n_local*32 + sc)*8];
      acc[0][ct] = mfma16(a0, bf, acc[0][ct]);
      acc[1][ct] = mfma16(a1, bf, acc[1][ct]);
    }
  }

  #pragma unroll
  for (int ct=0; ct<8; ++ct) {
    int n_g = nt*128 + ct*16 + l15;
    float bv = bias[n_g];
    #pragma unroll
    for (int rt=0; rt<2; ++rt) {
      #pragma unroll
      for (int q=0; q<4; ++q) {
        int r_g = m0 + rt*16 + l4*4 + q;
        if (r_g < M) out[(long)r_g*32000 + n_g] = acc[rt][ct][q] + bv;
      }
    }
  }
}

// ---------------------------------------------------------------------------
extern "C" void kernel_launch(void* const* d_in, const int* in_sizes, int n_in,
                              void* d_out, int out_size, void* d_ws, size_t ws_size,
                              hipStream_t stream)
{
  (void)in_sizes; (void)n_in; (void)out_size; (void)ws_size;
  const int*   ctx_ids  = (const int*)  d_in[0];
  const int*   ctx_mask = (const int*)  d_in[1];
  const float* img      = (const float*)d_in[2];
  const int*   tgt_ids  = (const int*)  d_in[3];
  const float* emb_text = (const float*)d_in[4];
  const float* Wih_t    = (const float*)d_in[5];
  const float* Whh_t    = (const float*)d_in[6];
  const float* bih_t    = (const float*)d_in[7];
  const float* bhh_t    = (const float*)d_in[8];
  const float* fuse_W   = (const float*)d_in[9];
  const float* fuse_b   = (const float*)d_in[10];
  const float* mem_init = (const float*)d_in[11];
  const float* Wih_c    = (const float*)d_in[12];
  const float* Whh_c    = (const float*)d_in[13];
  const float* bih_c    = (const float*)d_in[14];
  const float* bhh_c    = (const float*)d_in[15];
  const float* tok_emb  = (const float*)d_in[16];
  const float* Wih_d    = (const float*)d_in[17];
  const float* Whh_d    = (const float*)d_in[18];
  const float* bih_d    = (const float*)d_in[19];
  const float* bhh_d    = (const float*)d_in[20];
  const float* head_W   = (const float*)d_in[21];
  const float* head_b   = (const float*)d_in[22];
  float* out = (float*)d_out;
  char* ws = (char*)d_ws;

  size_t o = 0;
  auto alloc = [&](size_t bytes){ size_t r = o; o += (bytes + 255) & ~(size_t)255; return r; };
  unsigned short* wWih_t = (unsigned short*)(ws + alloc(768*256*2));
  unsigned short* wWhh_t = (unsigned short*)(ws + alloc(768*256*2));
  unsigned short* wWih_c = (unsigned short*)(ws + alloc(768*256*2));
  unsigned short* wWhh_c = (unsigned short*)(ws + alloc(768*256*2));
  unsigned short* wWih_d = (unsigned short*)(ws + alloc(768*256*2));
  unsigned short* wWhh_d = (unsigned short*)(ws + alloc(768*256*2));
  unsigned short* wFuse  = (unsigned short*)(ws + alloc(256*768*2));
  unsigned short* wHead  = (unsigned short*)(ws + alloc((size_t)32000*256*2));
  unsigned short* xg_t   = (unsigned short*)(ws + alloc((size_t)16384*768*2));
  unsigned short* xg_c   = (unsigned short*)(ws + alloc((size_t)512*768*2));
  unsigned short* xg_d   = (unsigned short*)(ws + alloc((size_t)2032*768*2));
  float*          tvec   = (float*)(ws + alloc((size_t)512*256*4));
  float*          zbuf   = (float*)(ws + alloc((size_t)512*256*4));
  float*          z2buf  = (float*)(ws + alloc((size_t)512*256*4));
  float*          h0buf  = (float*)(ws + alloc((size_t)16*256*4));
  unsigned short* outsb  = (unsigned short*)(ws + alloc((size_t)2048*256*2));

  // 0) weights -> bf16
  k_cvt<<<2048, 256, 0, stream>>>(head_W, wHead,
      Wih_t, Whh_t, Wih_c, Whh_c, Wih_d, Whh_d, fuse_W,
      wWih_t, wWhh_t, wWih_c, wWhh_c, wWih_d, wWhh_d, wFuse);

  // 1) xg for ctx text GRU: rows = (b*K+k)*L + l = 16384
  k_gemm<32,32,0><<<dim3(256,6), 256, 0, stream>>>(
      emb_text, 256, nullptr, 0, 256, ctx_ids, wWih_t, bih_t, 16384, 256, xg_t, 768);

  // 1b) xg for decoder (independent): rows = b*127 + t = 2032
  k_gemm<127,128,0><<<dim3(32,6), 256, 0, stream>>>(
      tok_emb, 256, nullptr, 0, 256, tgt_ids, wWih_d, bih_d, 2032, 256, xg_d, 768);

  // 2) ctx text GRU (masked), 512 rows -> tvec
  k_gru<<<32, 512, 0, stream>>>(wWhh_t, bhh_t, xg_t, ctx_mask,
                                nullptr, tvec, nullptr, 32);

  // 3) fuse: z = tanh([tvec|img] @ fuse_W^T + fuse_b), 512x256
  k_gemm<1,1,1><<<dim3(8,2), 256, 0, stream>>>(
      tvec, 256, img, 512, 256, nullptr, wFuse, fuse_b, 512, 768, zbuf, 256);

  // 4) memory scan -> z2
  k_mem<<<16, 64, 0, stream>>>(zbuf, mem_init, z2buf);

  // 5) xg for ctx GRU2 from z2 (rows b*32+t = 512)
  k_gemm<1,1,0><<<dim3(8,6), 256, 0, stream>>>(
      z2buf, 256, nullptr, 0, 256, nullptr, wWih_c, bih_c, 512, 256, xg_c, 768);

  // 6) ctx GRU2 -> h0
  k_gru<<<1, 512, 0, stream>>>(wWhh_c, bhh_c, xg_c, nullptr,
                               nullptr, h0buf, nullptr, 32);

  // 7) decoder GRU -> outs (bf16, 2032 rows)
  k_gru<<<1, 512, 0, stream>>>(wWhh_d, bhh_d, xg_d, nullptr,
                               h0buf, nullptr, outsb, 127);

  // 8) head: logits
  k_head<<<4000, 256, 0, stream>>>(outsb, wHead, head_b, out, 2032);
}